// Round 3
// baseline (3566.541 us; speedup 1.0000x reference)
//
#include <hip/hip_runtime.h>
#include <hip/hip_fp16.h>

// Bidirectional GRU: T=512, B=512, I=100, H=96, gates (r,z,n).
// R2: LDS-pipe was the bottleneck (12 cyc/ds_read_b128, CU-shared).
//  proj: x row is block-uniform -> scalar loads (s_load) + v_fma(vgpr_w, sgpr_x).
//  scan: 1 wave per chain, W_hh packed fp16 in VGPRs, h broadcast via
//        v_readlane -> SGPR, v_dot2_f32_f16 accumulate. No LDS, no barriers.
// R3: fix cvt_pkrtz return-type mismatch via bit_cast (compile-only change).

#define TT 512
#define BB 512
#define II 100
#define HH 96
#define GG 288   // 3*H

typedef _Float16 h2 __attribute__((ext_vector_type(2)));

__device__ __forceinline__ h2 pack2_(float a, float b) {
    return __builtin_bit_cast(h2, __builtin_amdgcn_cvt_pkrtz(a, b));
}
__device__ __forceinline__ int pack2i_(float a, float b) {
    return __builtin_bit_cast(int, __builtin_amdgcn_cvt_pkrtz(a, b));
}

__device__ __forceinline__ float fast_rcp(float x) { return __builtin_amdgcn_rcpf(x); }
__device__ __forceinline__ float sigmoidf_(float x) { return fast_rcp(1.f + __expf(-x)); }
__device__ __forceinline__ float tanhf_(float x) {
    float e = __expf(-2.f * x);
    return (1.f - e) * fast_rcp(1.f + e);
}

#if __has_builtin(__builtin_amdgcn_fdot2)
__device__ __forceinline__ float fdot2_(h2 a, h2 b, float c) {
    return __builtin_amdgcn_fdot2(a, b, c, false);
}
#else
__device__ __forceinline__ float fdot2_(h2 a, h2 b, float c) {
    return c + (float)a.x * (float)b.x + (float)a.y * (float)b.y;
}
#endif

// ---------------- input projection ----------------
// grid (1024, 2), block 288. Thread g keeps W_ih[g][:] in VGPRs; the x row is
// block-uniform so xr[k] loads become scalar (SMEM) loads -> pure VALU FMA.
__global__ __launch_bounds__(288) void proj_kernel(
    const float* __restrict__ x,
    const float* __restrict__ wih_f, const float* __restrict__ bih_f,
    const float* __restrict__ wih_b, const float* __restrict__ bih_b,
    __half* __restrict__ xp)
{
    const int dir = blockIdx.y;
    const int g = threadIdx.x;
    const float* __restrict__ w_ih = dir ? wih_b : wih_f;
    const float* __restrict__ b_ih = dir ? bih_b : bih_f;

    float w[II];
#pragma unroll
    for (int k = 0; k < II; ++k) w[k] = w_ih[g * II + k];
    const float bias = b_ih[g];

    __half* __restrict__ out = xp + (size_t)dir * (size_t)(TT * BB) * GG;
    const int m0 = blockIdx.x * 256;

    for (int mm = 0; mm < 256; ++mm) {
        const int m = m0 + mm;
        const float* __restrict__ xr = x + (size_t)m * II;  // block-uniform base
        float a0 = bias, a1 = 0.f, a2 = 0.f, a3 = 0.f;
#pragma unroll
        for (int k = 0; k < II; k += 4) {
            a0 += xr[k + 0] * w[k + 0];
            a1 += xr[k + 1] * w[k + 1];
            a2 += xr[k + 2] * w[k + 2];
            a3 += xr[k + 3] * w[k + 3];
        }
        const float acc = (a0 + a1) + (a2 + a3);
        size_t mo;
        if (dir == 0) {
            mo = (size_t)m;
        } else {
            const int t = m >> 9;            // m / 512
            const int b = m & 511;
            mo = (size_t)(TT - 1 - t) * BB + b;  // time-reversed storage
        }
        out[mo * GG + g] = __float2half(acc);
    }
}

// ---------------- recurrent scan ----------------
// grid (512, 2), block 64 (one wave per chain). Lane l owns gates
// {l, 64+l, 128+l, 192+l, 256+l(l<32)}. Gate classes: regs 0..2 are all
// sigmoid-class (r/z mix), reg3 = n[j=l], reg4 = n[j=64+l].
__global__ __launch_bounds__(64) void scan_kernel(
    const __half* __restrict__ xp,
    const float* __restrict__ whh_f, const float* __restrict__ bhh_f,
    const float* __restrict__ whh_b, const float* __restrict__ bhh_b,
    float* __restrict__ out)
{
    const int dir = blockIdx.y;
    const int b = blockIdx.x;
    const int l = threadIdx.x;
    const float* __restrict__ w_hh = dir ? whh_b : whh_f;
    const float* __restrict__ b_hh = dir ? bhh_b : bhh_f;

    int garr[5];
#pragma unroll
    for (int r = 0; r < 4; ++r) garr[r] = 64 * r + l;
    garr[4] = (l < 32) ? (256 + l) : 287;  // clamp: lanes>=32 compute a dummy gate

    // W_hh rows packed fp16: 5 x 48 half2 = 240 VGPRs
    h2 w2[5][48];
    float bias[5];
#pragma unroll
    for (int r = 0; r < 5; ++r) {
        const int g = garr[r];
        bias[r] = b_hh[g];
        const float* __restrict__ wr = w_hh + (size_t)g * HH;
#pragma unroll
        for (int p = 0; p < 48; ++p)
            w2[r][p] = pack2_(wr[2 * p], wr[2 * p + 1]);
    }

    const __half* __restrict__ xpd = xp + (size_t)dir * (size_t)(TT * BB) * GG;

    float h3 = 0.f, h4 = 0.f;        // h[j=l], h[j=64+l]
    int h2i3 = 0, h2i4 = 0;          // packed (h[2p],h[2p+1]) on even lanes

    __half xc[5], x1[5], x2[5];
#pragma unroll
    for (int r = 0; r < 5; ++r) xc[r] = xpd[((size_t)0 * BB + b) * GG + garr[r]];
#pragma unroll
    for (int r = 0; r < 5; ++r) x1[r] = xpd[((size_t)1 * BB + b) * GG + garr[r]];

    for (int t = 0; t < TT; ++t) {
        // prefetch t+2 (clamped; unused tail reads are harmless)
        const int tp = (t + 2 < TT) ? t + 2 : TT - 1;
        const size_t pbase = ((size_t)tp * BB + b) * GG;
#pragma unroll
        for (int r = 0; r < 5; ++r) x2[r] = xpd[pbase + garr[r]];

        // hp = h . W_hh[g] + b_hh[g], h broadcast through SGPRs
        float acc[5];
#pragma unroll
        for (int r = 0; r < 5; ++r) acc[r] = bias[r];
#pragma unroll
        for (int p = 0; p < 48; ++p) {
            const int hs = (p < 32) ? __builtin_amdgcn_readlane(h2i3, 2 * p)
                                    : __builtin_amdgcn_readlane(h2i4, 2 * (p - 32));
            const h2 hh = __builtin_bit_cast(h2, hs);
#pragma unroll
            for (int r = 0; r < 5; ++r) acc[r] = fdot2_(w2[r][p], hh, acc[r]);
        }

        // sigmoid class: regs 0..2 (gates 0..191 = all r and z)
        const float s0 = sigmoidf_(acc[0] + __half2float(xc[0]));
        const float s1 = sigmoidf_(acc[1] + __half2float(xc[1]));
        const float s2 = sigmoidf_(acc[2] + __half2float(xc[2]));

        // regroup r,z per n-slot:
        //  j=l   : r=s0(own);           z = l<32 ? s1[lane l+32] : s2[lane l-32]
        //  j=64+l: r=s1(own, l<32);     z = s2[lane l+32]
        const int xl = (l + 32) & 63;
        const float zs1 = __shfl(s1, xl);
        const float zs2 = __shfl(s2, xl);
        const float z3 = (l < 32) ? zs1 : zs2;
        const float z4 = zs2;
        const float r3 = s0;
        const float r4 = s1;

        const float n3 = tanhf_(__half2float(xc[3]) + r3 * acc[3]);
        const float n4 = tanhf_(__half2float(xc[4]) + r4 * acc[4]);
        h3 = (1.f - z3) * n3 + z3 * h3;
        h4 = (1.f - z4) * n4 + z4 * h4;

        // store
        const int orow = dir ? (TT - 1 - t) : t;
        float* __restrict__ o = out + ((size_t)orow * BB + b) * (2 * HH) + dir * HH;
        o[l] = h3;
        if (l < 32) o[64 + l] = h4;

        // repack h pairs for next step's readlane broadcast (even lanes matter)
        const float h3n = __shfl_down(h3, 1);
        const float h4n = __shfl_down(h4, 1);
        h2i3 = pack2i_(h3, h3n);
        h2i4 = pack2i_(h4, h4n);

        // rotate xp ring
#pragma unroll
        for (int r = 0; r < 5; ++r) { xc[r] = x1[r]; x1[r] = x2[r]; }
    }
}

__global__ void sentinel_kernel(float* out) {
    if (threadIdx.x == 0 && blockIdx.x == 0) out[0] = 1e9f;  // ws too small marker
}

extern "C" void kernel_launch(void* const* d_in, const int* in_sizes, int n_in,
                              void* d_out, int out_size, void* d_ws, size_t ws_size,
                              hipStream_t stream)
{
    const float* x     = (const float*)d_in[0];
    const float* wih_f = (const float*)d_in[1];
    const float* whh_f = (const float*)d_in[2];
    const float* bih_f = (const float*)d_in[3];
    const float* bhh_f = (const float*)d_in[4];
    const float* wih_b = (const float*)d_in[5];
    const float* whh_b = (const float*)d_in[6];
    const float* bih_b = (const float*)d_in[7];
    const float* bhh_b = (const float*)d_in[8];
    float* out = (float*)d_out;

    const size_t ws_needed = (size_t)2 * TT * BB * GG * sizeof(__half);  // ~302 MB
    if (ws_size < ws_needed) {
        sentinel_kernel<<<1, 64, 0, stream>>>(out);
        return;
    }
    __half* xp = (__half*)d_ws;

    dim3 pgrid(TT * BB / 256, 2);
    proj_kernel<<<pgrid, 288, 0, stream>>>(x, wih_f, bih_f, wih_b, bih_b, xp);

    dim3 sgrid(BB, 2);
    scan_kernel<<<sgrid, 64, 0, stream>>>(xp, whh_f, bhh_f, whh_b, bhh_b, out);
}